// Round 1
// 12884.665 us; speedup vs baseline: 1.5668x; 1.5668x over previous
//
#include <hip/hip_runtime.h>
#include <math.h>

#define LNUM 4
#define DM 768
#define DI 1536
#define DS_N 16
#define DR 48
#define KCV 4
#define VV 32000
#define BB 2
#define SEQ 2048
#define MT (BB*SEQ)     // 4096 tokens
#define XPD 80          // DR + 2*DS

typedef __attribute__((ext_vector_type(8))) _Float16 half8;
typedef __attribute__((ext_vector_type(4))) _Float16 half4;
typedef __attribute__((ext_vector_type(4))) float f32x4;

static __device__ __forceinline__ float siluf(float x){ return x/(1.f+expf(-x)); }

__device__ __forceinline__ void gl_lds16(const void* g, void* l){
  __builtin_amdgcn_global_load_lds((const __attribute__((address_space(1))) unsigned int*)g,
                                   (__attribute__((address_space(3))) unsigned int*)l, 16, 0, 0);
}

// ---------------- embedding (optionally sequence-flipped ids) ----------------
__global__ void embed_k(const int* __restrict__ ids, const float* __restrict__ emb,
                        float* __restrict__ h, int flip){
  size_t i = (size_t)blockIdx.x*blockDim.x + threadIdx.x;
  size_t n = (size_t)MT*(DM/4);
  if(i>=n) return;
  int t = (int)(i/(DM/4)); int d4 = (int)(i%(DM/4));
  int b = t/SEQ, s = t%SEQ;
  int tok = flip ? ids[b*SEQ + (SEQ-1-s)] : ids[t];
  const float4* src = (const float4*)(emb + (size_t)tok*DM);
  float4* dst = (float4*)(h + (size_t)t*DM);
  dst[d4] = src[d4];
}

// ---------------- fp32 -> fp16 convert (n must be multiple of 4) -------------
__global__ void f2h_k(const float* __restrict__ x, _Float16* __restrict__ o, size_t n4){
  size_t i = (size_t)blockIdx.x*blockDim.x + threadIdx.x;
  if(i>=n4) return;
  float4 v = ((const float4*)x)[i];
  half4 h; h[0]=(_Float16)v.x; h[1]=(_Float16)v.y; h[2]=(_Float16)v.z; h[3]=(_Float16)v.w;
  ((half4*)o)[i] = h;
}

// ---------------- RMSNorm with fp16 output; supports wide output (combined) --
// out[t, ooff + i] (row stride ldo) = rms(x[ti,:]) ; ti = flip? mirrored row
__global__ void rmsnorm_h_k(const float* __restrict__ x, const float* __restrict__ w,
                            _Float16* __restrict__ o, int dim, int ldo, int ooff, int flip){
  int t = blockIdx.x;
  int b = t/SEQ, s = t%SEQ;
  int ti = flip ? (b*SEQ + (SEQ-1-s)) : t;
  const float* xr = x + (size_t)ti*dim;
  float ss = 0.f;
  for(int i=threadIdx.x;i<dim;i+=blockDim.x){ float v=xr[i]; ss += v*v; }
  for(int off=32;off>0;off>>=1) ss += __shfl_down(ss,off,64);
  __shared__ float red[8];
  int wid = threadIdx.x>>6, lane = threadIdx.x&63;
  if(lane==0) red[wid]=ss;
  __syncthreads();
  if(threadIdx.x==0){
    float tot=0.f; int nw = blockDim.x>>6;
    for(int i=0;i<nw;i++) tot += red[i];
    red[0] = rsqrtf(tot/(float)dim + 1e-5f);
  }
  __syncthreads();
  float sc = red[0];
  _Float16* orow = o + (size_t)t*ldo + ooff;
  for(int i=threadIdx.x;i<dim;i+=blockDim.x) orow[i] = (_Float16)(xr[i]*sc*w[i]);
}

// ---------------- fp16 MFMA GEMM:  C[m,n] = (ADD?C:0) + sum_k A[m,k]*W[n,k] --
// A: (M,K) fp16 row-major compact; W: (N,K) fp16 row-major compact; C fp32 (M,N).
// Requires M%128==0, N%128==0, K%32==0.
// 128x128 tile, BK=32, 256 threads = 4 waves (2x2 of 64x64), 4x4 16x16x32 frags.
// LDS layout [kg][row][8] fp16: kg = k-chunk-of-8 => conflict-free ds_read_b128,
// matches global_load_lds linear-dest constraint (1KB per wave-instruction).
template<bool ADD>
__global__ __launch_bounds__(256) void gemm_h(const _Float16* __restrict__ A,
                 const _Float16* __restrict__ W, float* __restrict__ C,
                 int M, int N, int K){
  __shared__ __align__(16) _Float16 Asub[4][128][8];
  __shared__ __align__(16) _Float16 Bsub[4][128][8];
  int tid  = threadIdx.x;
  int lane = tid & 63;
  int wave = tid >> 6;
  int wm = (wave>>1)*64, wn = (wave&1)*64;
  int bm = blockIdx.y*128, bn = blockIdx.x*128;

  f32x4 acc[4][4];
  #pragma unroll
  for(int i=0;i<4;i++)
    #pragma unroll
    for(int j=0;j<4;j++) acc[i][j] = (f32x4){0.f,0.f,0.f,0.f};

  // staging decomposition: 16B unit u covers (kg = u>>7, row = u&127)
  int u0 = tid, u1 = 256 + tid;
  int kg0 = u0>>7, r0 = u0&127;
  int kg1 = u1>>7, r1 = u1&127;
  const _Float16* Ag0 = A + (size_t)(bm+r0)*K + kg0*8;
  const _Float16* Ag1 = A + (size_t)(bm+r1)*K + kg1*8;
  const _Float16* Wg0 = W + (size_t)(bn+r0)*K + kg0*8;
  const _Float16* Wg1 = W + (size_t)(bn+r1)*K + kg1*8;
  _Float16* Al0 = &Asub[0][0][0] + (size_t)u0*8;
  _Float16* Al1 = &Asub[0][0][0] + (size_t)u1*8;
  _Float16* Bl0 = &Bsub[0][0][0] + (size_t)u0*8;
  _Float16* Bl1 = &Bsub[0][0][0] + (size_t)u1*8;

  int fr = lane & 15, fk = lane >> 4;

  for(int k0=0;k0<K;k0+=32){
    gl_lds16(Ag0 + k0, Al0);
    gl_lds16(Ag1 + k0, Al1);
    gl_lds16(Wg0 + k0, Bl0);
    gl_lds16(Wg1 + k0, Bl1);
    __syncthreads();
    half8 av[4], bv[4];
    #pragma unroll
    for(int mf=0;mf<4;mf++) av[mf] = *(const half8*)&Asub[fk][wm+mf*16+fr][0];
    #pragma unroll
    for(int nf=0;nf<4;nf++) bv[nf] = *(const half8*)&Bsub[fk][wn+nf*16+fr][0];
    #pragma unroll
    for(int mf=0;mf<4;mf++)
      #pragma unroll
      for(int nf=0;nf<4;nf++)
        acc[mf][nf] = __builtin_amdgcn_mfma_f32_16x16x32_f16(av[mf], bv[nf], acc[mf][nf], 0, 0, 0);
    __syncthreads();
  }

  // C/D mapping (m89): col = lane&15, row = (lane>>4)*4 + j
  int cr = (lane>>4)*4, cc = lane&15;
  #pragma unroll
  for(int mf=0;mf<4;mf++){
    int grow = bm + wm + mf*16 + cr;
    #pragma unroll
    for(int j=0;j<4;j++){
      float* crow = C + (size_t)(grow+j)*N + bn + wn + cc;
      #pragma unroll
      for(int nf=0;nf<4;nf++){
        float v = acc[mf][nf][j];
        if(ADD) crow[nf*16] += v; else crow[nf*16] = v;
      }
    }
  }
}

// ---------------- fp32 tiled GEMM (kept for small shapes: dbc N=80, dt K=48) -
template<bool ADD>
__global__ __launch_bounds__(256) void gemm_nt(const float* __restrict__ A, int lda,
                        const float* __restrict__ W, float* __restrict__ C,
                        int Mm, int Nn, int Kk){
  __shared__ float As[8][132];
  __shared__ float Bs[8][132];
  int tid = threadIdx.x;
  int tx = tid & 15, ty = tid >> 4;
  int bm = blockIdx.y*128, bn = blockIdx.x*128;
  float acc[8][8];
  #pragma unroll
  for(int i=0;i<8;i++)
    #pragma unroll
    for(int j=0;j<8;j++) acc[i][j]=0.f;

  int lr = tid>>1;           // 0..127 (tile row)
  int kq = (tid&1)*4;        // 0 or 4
  for(int k0=0;k0<Kk;k0+=8){
    float4 va = make_float4(0,0,0,0), vb = make_float4(0,0,0,0);
    int gm = bm+lr, gn = bn+lr;
    if(gm<Mm) va = *(const float4*)(A + (size_t)gm*lda + k0 + kq);
    if(gn<Nn) vb = *(const float4*)(W + (size_t)gn*Kk  + k0 + kq);
    As[kq+0][lr]=va.x; As[kq+1][lr]=va.y; As[kq+2][lr]=va.z; As[kq+3][lr]=va.w;
    Bs[kq+0][lr]=vb.x; Bs[kq+1][lr]=vb.y; Bs[kq+2][lr]=vb.z; Bs[kq+3][lr]=vb.w;
    __syncthreads();
    #pragma unroll
    for(int kk=0;kk<8;kk++){
      float a[8], bv[8];
      #pragma unroll
      for(int i=0;i<8;i++) a[i]  = As[kk][ty*8+i];
      #pragma unroll
      for(int j=0;j<8;j++) bv[j] = Bs[kk][tx*8+j];
      #pragma unroll
      for(int i=0;i<8;i++)
        #pragma unroll
        for(int j=0;j<8;j++) acc[i][j] += a[i]*bv[j];
    }
    __syncthreads();
  }
  #pragma unroll
  for(int i=0;i<8;i++){
    int gm = bm + ty*8 + i; if(gm>=Mm) continue;
    #pragma unroll
    for(int j=0;j<8;j++){
      int gn = bn + tx*8 + j; if(gn>=Nn) continue;
      size_t o = (size_t)gm*Nn + gn;
      C[o] = (ADD ? C[o] : 0.f) + acc[i][j];
    }
  }
}

// ---------------- causal depthwise conv (K=4) + SiLU ------------------------
__global__ void conv_silu_k(const float* __restrict__ xz, const float* __restrict__ cw,
                            const float* __restrict__ cb, float* __restrict__ xc){
  size_t i = (size_t)blockIdx.x*blockDim.x + threadIdx.x;
  if(i>=(size_t)MT*DI) return;
  long t = (long)(i/DI); int d = (int)(i%DI); int s = (int)(t%SEQ);
  float acc = cb[d];
  #pragma unroll
  for(int k=0;k<KCV;k++){
    int sp = s + k - (KCV-1);
    if(sp>=0){
      long tt = t + (k - (KCV-1));
      acc += xz[(size_t)tt*(2*DI) + d]*cw[d*KCV + k];
    }
  }
  xc[i] = siluf(acc);
}

// ---------------- dt = softplus(dtpre + dtb) (in place) ---------------------
__global__ void softplus_k(float* __restrict__ dtv, const float* __restrict__ dtb){
  size_t i = (size_t)blockIdx.x*blockDim.x + threadIdx.x;
  if(i>=(size_t)MT*DI) return;
  int d = (int)(i%DI);
  float x = dtv[i] + dtb[d];
  dtv[i] = (x>20.f) ? x : log1pf(expf(x));
}

// ---------------- selective-scan. One wave handles 4 d-channels x 16 states --
__global__ void scan_k(const float* __restrict__ dt, const float* __restrict__ xc,
                       const float* __restrict__ dbc, const float* __restrict__ Alog,
                       const float* __restrict__ Dp, float* __restrict__ y){
  int lane = threadIdx.x;     // 64
  int ln = lane & 15;         // state index n
  int ld = lane >> 4;         // which of 4 channels
  int d = blockIdx.x*4 + ld;
  int b = blockIdx.y;
  float Acoef = -expf(Alog[d*DS_N + ln]);
  float Dv = Dp[d];
  float h = 0.f;
  size_t tbase = (size_t)b*SEQ;
  #pragma unroll 2
  for(int s=0;s<SEQ;s++){
    size_t t = tbase + s;
    float dtv = dt[t*DI + d];
    float xv  = xc[t*DI + d];
    float Bv  = dbc[t*XPD + DR + ln];
    float Cv  = dbc[t*XPD + DR + DS_N + ln];
    float e = expf(dtv*Acoef);
    h = e*h + (dtv*xv)*Bv;
    float c = h*Cv;
    c += __shfl_xor(c, 8, 16);
    c += __shfl_xor(c, 4, 16);
    c += __shfl_xor(c, 2, 16);
    c += __shfl_xor(c, 1, 16);
    if(ln==0) y[t*DI + d] = c + Dv*xv;
  }
}

// ---------------- yh = (fp16)(y * silu(z));  z = xz[:, DI:] ------------------
__global__ void gate_h_k(const float* __restrict__ y, const float* __restrict__ xz,
                         _Float16* __restrict__ yh){
  size_t i = (size_t)blockIdx.x*blockDim.x + threadIdx.x;
  if(i>=(size_t)MT*DI) return;
  size_t t = i/DI; int d = (int)(i%DI);
  float z = xz[t*(2*DI) + DI + d];
  yh[i] = (_Float16)(y[i]*siluf(z));
}

// ---------------- loss -------------------------------------------------------
__global__ void zero_k(float* a){ a[0]=0.f; a[1]=0.f; }

__global__ void loss_k(const float* __restrict__ logits, const int* __restrict__ labels,
                       float* __restrict__ accum){
  int t = blockIdx.x;
  const float* row = logits + (size_t)t*VV;
  float m = -1e30f, ssum = 0.f;
  for(int i=threadIdx.x;i<VV;i+=256){
    float x = row[i];
    if(x>m){ ssum = ssum*expf(m-x) + 1.f; m = x; }
    else    ssum += expf(x-m);
  }
  __shared__ float sm[256], sv[256];
  sm[threadIdx.x]=m; sv[threadIdx.x]=ssum;
  __syncthreads();
  for(int off=128;off;off>>=1){
    if(threadIdx.x<off){
      float m1=sm[threadIdx.x], m2=sm[threadIdx.x+off];
      float s1=sv[threadIdx.x], s2=sv[threadIdx.x+off];
      float M = fmaxf(m1,m2);
      sm[threadIdx.x]=M;
      sv[threadIdx.x]=s1*expf(m1-M)+s2*expf(m2-M);
    }
    __syncthreads();
  }
  if(threadIdx.x==0){
    int lab = labels[t];
    if(lab != -100){
      float logZ = sm[0] + logf(sv[0]);
      float nll = logZ - row[lab];
      atomicAdd(&accum[0], nll);
      atomicAdd(&accum[1], 1.f);
    }
  }
}

__global__ void final_k(const float* __restrict__ accum, float* __restrict__ out){
  out[0] = accum[0]/fmaxf(accum[1],1.f);
}

// ---------------- host -------------------------------------------------------
extern "C" void kernel_launch(void* const* d_in, const int* in_sizes, int n_in,
                              void* d_out, int out_size, void* d_ws, size_t ws_size,
                              hipStream_t stream){
  (void)in_sizes; (void)n_in; (void)out_size; (void)ws_size;
  const int* ids    = (const int*)d_in[0];
  const int* labels = (const int*)d_in[1];
  const float* lm_w = (const float*)d_in[26];
  float* ws = (float*)d_ws;
  float* logits = (float*)d_out;

  size_t off=0;
  float* hbuf0 = ws+off; off += (size_t)MT*DM;
  float* hbuf1 = ws+off; off += (size_t)MT*DM;
  // ---- scratch region (reused for fp16 lm_w after both dirs complete) ----
  size_t scratch_off = off;
  float* xz    = ws+off; off += (size_t)MT*2*DI;
  float* xc    = ws+off; off += (size_t)MT*DI;
  float* dbc   = ws+off; off += (size_t)MT*XPD;
  float* dtv   = ws+off; off += (size_t)MT*DI;
  float* ybuf  = ws+off; off += (size_t)MT*DI;
  // ---- fp16 buffers (float-slot accounting: 2 halves per slot) ----
  _Float16* comb_h = (_Float16*)(ws+off); off += (size_t)MT*2*DM/2;
  _Float16* xbuf_h = (_Float16*)(ws+off); off += (size_t)MT*DM/2;
  _Float16* ybuf_h = (_Float16*)(ws+off); off += (size_t)MT*DI/2;
  _Float16* inw_h  = (_Float16*)(ws+off); off += (size_t)LNUM*2*DI*DM/2;
  _Float16* outw_h = (_Float16*)(ws+off); off += (size_t)LNUM*DM*DI/2;
  float* accum = ws+off; off += 2;
  _Float16* lmw_h = (_Float16*)(ws + scratch_off);  // 49.15M halves fits in 31.8M-float scratch

  const int PW_BLOCKS = (int)(((size_t)MT*DI + 255)/256);

  for(int dir=0; dir<2; dir++){
    const float* emb   = (const float*)d_in[2+12*dir+0];
    const float* normw = (const float*)d_in[2+12*dir+1];
    const float* inw   = (const float*)d_in[2+12*dir+2];
    const float* convw = (const float*)d_in[2+12*dir+3];
    const float* convb = (const float*)d_in[2+12*dir+4];
    const float* xpw   = (const float*)d_in[2+12*dir+5];
    const float* dtw   = (const float*)d_in[2+12*dir+6];
    const float* dtbp  = (const float*)d_in[2+12*dir+7];
    const float* Alog  = (const float*)d_in[2+12*dir+8];
    const float* Dp    = (const float*)d_in[2+12*dir+9];
    const float* outw  = (const float*)d_in[2+12*dir+10];
    const float* fnorm = (const float*)d_in[2+12*dir+11];
    float* h = dir ? hbuf1 : hbuf0;

    // convert this direction's big weights to fp16
    { size_t n4 = (size_t)LNUM*2*DI*DM/4;
      f2h_k<<<(int)((n4+255)/256),256,0,stream>>>(inw, inw_h, n4); }
    { size_t n4 = (size_t)LNUM*DM*DI/4;
      f2h_k<<<(int)((n4+255)/256),256,0,stream>>>(outw, outw_h, n4); }

    embed_k<<<(MT*(DM/4)+255)/256,256,0,stream>>>(ids, emb, h, dir);

    for(int l=0;l<LNUM;l++){
      rmsnorm_h_k<<<MT,256,0,stream>>>(h, normw+l*DM, xbuf_h, DM, DM, 0, 0);
      { dim3 g(2*DI/128, MT/128);
        gemm_h<false><<<g,256,0,stream>>>(xbuf_h, inw_h+(size_t)l*2*DI*DM, xz, MT, 2*DI, DM); }
      conv_silu_k<<<PW_BLOCKS,256,0,stream>>>(xz, convw+l*DI*KCV, convb+l*DI, xc);
      { dim3 g((XPD+127)/128,(MT+127)/128);
        gemm_nt<false><<<g,256,0,stream>>>(xc, DI, xpw+(size_t)l*XPD*DI, dbc, MT, XPD, DI); }
      { dim3 g((DI+127)/128,(MT+127)/128);
        gemm_nt<false><<<g,256,0,stream>>>(dbc, XPD, dtw+(size_t)l*DI*DR, dtv, MT, DI, DR); }
      softplus_k<<<PW_BLOCKS,256,0,stream>>>(dtv, dtbp+l*DI);
      { dim3 g(DI/4, BB);
        scan_k<<<g,64,0,stream>>>(dtv, xc, dbc, Alog+(size_t)l*DI*DS_N, Dp+l*DI, ybuf); }
      gate_h_k<<<PW_BLOCKS,256,0,stream>>>(ybuf, xz, ybuf_h);
      { dim3 g(DM/128, MT/128);
        gemm_h<true><<<g,256,0,stream>>>(ybuf_h, outw_h+(size_t)l*DM*DI, h, MT, DM, DI); }
    }
    // final rms -> combined (fp16); bw half is sequence-flipped back
    rmsnorm_h_k<<<MT,256,0,stream>>>(h, fnorm, comb_h, DM, 2*DM, dir?DM:0, dir);
  }

  // LM head: convert weight to fp16 (scratch now free), then MFMA GEMM
  { size_t n4 = (size_t)VV*2*DM/4;
    f2h_k<<<(int)((n4+255)/256),256,0,stream>>>(lm_w, lmw_h, n4); }
  { dim3 g(VV/128, MT/128);
    gemm_h<false><<<g,256,0,stream>>>(comb_h, lmw_h, logits, MT, VV, 2*DM); }

  zero_k<<<1,1,0,stream>>>(accum);
  loss_k<<<MT,256,0,stream>>>(logits, labels, accum);
  final_k<<<1,1,0,stream>>>(accum, logits + (size_t)MT*VV);
}